// Round 5
// baseline (192.945 us; speedup 1.0000x reference)
//
#include <hip/hip_runtime.h>

// MechanisticNRTLLoss — B=1e6 samples, scalar fp32 loss.
// R5: single-stage coalesced LDS staging. Model: R1-R4 are bound by per-CU
// L1 line-transaction throughput (~690 lines/wave scattered ≈ 168k cyc/CU ≈
// the invariant 63-69us). Coalesced float4 staging cuts this 4.3x. One
// barrier only (R3's two-phase structure serialized); MSE fused into the
// pred/target staging loop so target never touches LDS; T stays a direct
// coalesced global load. Compute math identical to R2/R4.

constexpr float ALPHA    = 0.3f;
constexpr float R_GAS    = 8.314462618f;
constexpr float EPS      = 1e-12f;
constexpr float TAU_CLIP = 10.0f;
constexpr float LN_CLIP  = 20.0f;
constexpr float EPS_FD   = 1e-4f;

constexpr float LOG2E = 1.44269504088896340736f;
constexpr float LN2   = 0.69314718055994530942f;

__device__ __forceinline__ float clipf(float v, float lo, float hi) {
    return fminf(fmaxf(v, lo), hi);
}
__device__ __forceinline__ float fast_rcp(float x) { return __builtin_amdgcn_rcpf(x); }

struct Mats {
    float tau[3][3];
    float G[3][3];
    float tG[3][3];
};

__device__ __forceinline__ void ln_gamma3(const float x[3], const Mats& M, float lg[3]) {
    float ratio[3], invd[3];
#pragma unroll
    for (int i = 0; i < 3; ++i) {
        float d = x[0] * M.G[0][i] + x[1] * M.G[1][i] + x[2] * M.G[2][i];
        d = fmaxf(d, EPS);
        float A = x[0] * M.tG[0][i] + x[1] * M.tG[1][i] + x[2] * M.tG[2][i];
        float inv = fast_rcp(d);
        invd[i] = inv;
        ratio[i] = A * inv;
    }
#pragma unroll
    for (int i = 0; i < 3; ++i) {
        float s = ratio[i];
#pragma unroll
        for (int j = 0; j < 3; ++j) {
            s += x[j] * M.G[i][j] * invd[j] * (M.tau[i][j] - ratio[j]);
        }
        lg[i] = clipf(s, -LN_CLIP, LN_CLIP);
    }
}

__device__ __forceinline__ void renorm3(float x[3]) {
    x[0] = fmaxf(x[0], 0.0f);
    x[1] = fmaxf(x[1], 0.0f);
    x[2] = fmaxf(x[2], 0.0f);
    float inv = fast_rcp(fmaxf(x[0] + x[1] + x[2], EPS));
    x[0] *= inv; x[1] *= inv; x[2] *= inv;
}

__global__ __launch_bounds__(256) void nrtl_loss_kernel(
    const float* __restrict__ pred,   // (B,6)
    const float* __restrict__ target, // (B,6)
    const float* __restrict__ Tarr,   // (B,)
    const float* __restrict__ g,      // (B,3,3)
    const float* __restrict__ dirs,   // (2,B,3)
    const float* __restrict__ noise,  // (4,B,3)
    float* __restrict__ partials, int B)
{
    // LDS slabs (floats): pred[0,1536) g[1536,3840) dirs[3840,5376) noise[5376,8448)
    __shared__ __align__(16) float sh[8448];
    float* s_pred  = sh;           // 256*6
    float* s_g     = sh + 1536;    // 256*9
    float* s_dirs  = sh + 3840;    // 2*768
    float* s_noise = sh + 5376;    // 4*768

    const int t  = threadIdx.x;
    const int s0 = blockIdx.x * 256;
    const int ns = min(256, B - s0);

    const float invB  = 1.0f / (float)B;
    const float SUP_W = invB * (1.0f / 6.0f);
    const float PHY_W = invB * (1.0f / 3.0f);
    const float GD_W  = invB * 0.1f * 0.5f;
    const float TPD_W = invB * 0.1f * 0.25f;

    float contrib = 0.0f;

    if (ns == 256) {
        // ---- fast path: fully unrolled coalesced float4 staging ----
        const float4* pg4 = (const float4*)(pred   + (size_t)s0 * 6);
        const float4* tg4 = (const float4*)(target + (size_t)s0 * 6);
        const float4* gg4 = (const float4*)(g      + (size_t)s0 * 9);
        float4* sp4 = (float4*)s_pred;
        float4* sg4 = (float4*)s_g;

        // pred/target: 384 float4 each; MSE fused, target never stored
        {
            float4 pa = pg4[t], ta = tg4[t];
            sp4[t] = pa;
            float dx = pa.x - ta.x, dy = pa.y - ta.y, dz = pa.z - ta.z, dw = pa.w - ta.w;
            contrib += SUP_W * (dx * dx + dy * dy + dz * dz + dw * dw);
            if (t < 128) {
                float4 pb = pg4[256 + t], tb = tg4[256 + t];
                sp4[256 + t] = pb;
                float ex = pb.x - tb.x, ey = pb.y - tb.y, ez = pb.z - tb.z, ew = pb.w - tb.w;
                contrib += SUP_W * (ex * ex + ey * ey + ez * ez + ew * ew);
            }
        }
        // g: 576 float4
        sg4[t]       = gg4[t];
        sg4[256 + t] = gg4[256 + t];
        if (t < 64) sg4[512 + t] = gg4[512 + t];
        // dirs: 2 x 192 float4
#pragma unroll
        for (int d = 0; d < 2; ++d)
            if (t < 192)
                ((float4*)(s_dirs + d * 768))[t] =
                    ((const float4*)(dirs + ((size_t)d * B + s0) * 3))[t];
        // noise: 4 x 192 float4
#pragma unroll
        for (int tr = 0; tr < 4; ++tr)
            if (t < 192)
                ((float4*)(s_noise + tr * 768))[t] =
                    ((const float4*)(noise + ((size_t)tr * B + s0) * 3))[t];
    } else {
        // ---- tail path: bounds-checked scalar staging ----
        const float* pg = pred   + (size_t)s0 * 6;
        const float* tg = target + (size_t)s0 * 6;
        for (int j = t; j < ns * 6; j += 256) {
            float pv = pg[j], tv = tg[j];
            s_pred[j] = pv;
            float d = pv - tv;
            contrib += SUP_W * d * d;
        }
        const float* gg = g + (size_t)s0 * 9;
        for (int j = t; j < ns * 9; j += 256) s_g[j] = gg[j];
        for (int d = 0; d < 2; ++d) {
            const float* dg = dirs + ((size_t)d * B + s0) * 3;
            for (int j = t; j < ns * 3; j += 256) s_dirs[d * 768 + j] = dg[j];
        }
        for (int tr = 0; tr < 4; ++tr) {
            const float* ng = noise + ((size_t)tr * B + s0) * 3;
            for (int j = t; j < ns * 3; j += 256) s_noise[tr * 768 + j] = ng[j];
        }
    }
    __syncthreads();

    if (t < ns) {
        float xE[3] = {s_pred[t * 6],     s_pred[t * 6 + 1], s_pred[t * 6 + 2]};
        float xR[3] = {s_pred[t * 6 + 3], s_pred[t * 6 + 4], s_pred[t * 6 + 5]};
        renorm3(xE);
        renorm3(xR);

        const float Tc = fmaxf(Tarr[s0 + t], 1.0f);   // coalesced direct load
        const float invRT = fast_rcp(R_GAS * Tc);
        Mats M;
#pragma unroll
        for (int a = 0; a < 3; ++a) {
#pragma unroll
            for (int b = 0; b < 3; ++b) {
                float ta = clipf(s_g[t * 9 + a * 3 + b] * invRT, -TAU_CLIP, TAU_CLIP);
                float Gv = __builtin_amdgcn_exp2f((-ALPHA * LOG2E) * ta);
                M.tau[a][b] = ta;
                M.G[a][b]   = Gv;
                M.tG[a][b]  = ta * Gv;
            }
        }

        float lgE[3], lgR[3];
        ln_gamma3(xE, M, lgE);
        ln_gamma3(xR, M, lgR);

        float logxE[3];
        float phy = 0.0f;
#pragma unroll
        for (int k = 0; k < 3; ++k) {
            logxE[k] = LN2 * __builtin_amdgcn_logf(fmaxf(xE[k], EPS));
            float logxR = LN2 * __builtin_amdgcn_logf(fmaxf(xR[k], EPS));
            float r = logxE[k] + lgE[k] - logxR - lgR[k];
            phy += r * r;
        }
        contrib += PHY_W * phy;

        float gdsum = 0.0f;
#pragma unroll
        for (int d = 0; d < 2; ++d) {
            float xp[3], xm[3];
#pragma unroll
            for (int k = 0; k < 3; ++k) {
                float dvk = s_dirs[d * 768 + t * 3 + k];
                xp[k] = xE[k] + EPS_FD * dvk;
                xm[k] = xE[k] - EPS_FD * dvk;
            }
            renorm3(xp);
            renorm3(xm);
            float lgp[3], lgm[3];
            ln_gamma3(xp, M, lgp);
            ln_gamma3(xm, M, lgm);
            float gd = 0.0f;
            const float inv2e = 0.5f / EPS_FD;
#pragma unroll
            for (int k = 0; k < 3; ++k) gd += xE[k] * ((lgp[k] - lgm[k]) * inv2e);
            gdsum += gd * gd;
        }
        contrib += GD_W * gdsum;

        float tpdsum = 0.0f;
#pragma unroll
        for (int tr = 0; tr < 4; ++tr) {
            float w[3];
#pragma unroll
            for (int k = 0; k < 3; ++k) w[k] = xE[k] + s_noise[tr * 768 + t * 3 + k];
            renorm3(w);
            float lgw[3];
            ln_gamma3(w, M, lgw);
            float tpd = 0.0f;
#pragma unroll
            for (int k = 0; k < 3; ++k) {
                float logw = LN2 * __builtin_amdgcn_logf(fmaxf(w[k], EPS));
                tpd += w[k] * (logw + lgw[k] - logxE[k] - lgE[k]);
            }
            tpdsum += fmaxf(-tpd, 0.0f);  // MARGIN = 0
        }
        contrib += TPD_W * tpdsum;
    }

    // ---- block reduction ----
#pragma unroll
    for (int off = 32; off > 0; off >>= 1)
        contrib += __shfl_down(contrib, off, 64);

    __shared__ float ssum[4];
    const int lane = threadIdx.x & 63;
    const int wid  = threadIdx.x >> 6;
    if (lane == 0) ssum[wid] = contrib;
    __syncthreads();
    if (threadIdx.x == 0) {
        partials[blockIdx.x] = ssum[0] + ssum[1] + ssum[2] + ssum[3];
    }
}

__global__ __launch_bounds__(256) void reduce_kernel(
    const float* __restrict__ partials, int n, float* __restrict__ out)
{
    double sacc = 0.0;
    for (int j = threadIdx.x; j < n; j += 256) sacc += (double)partials[j];
#pragma unroll
    for (int off = 32; off > 0; off >>= 1)
        sacc += __shfl_down(sacc, off, 64);
    __shared__ double ds[4];
    const int lane = threadIdx.x & 63;
    const int wid  = threadIdx.x >> 6;
    if (lane == 0) ds[wid] = sacc;
    __syncthreads();
    if (threadIdx.x == 0) out[0] = (float)(ds[0] + ds[1] + ds[2] + ds[3]);
}

extern "C" void kernel_launch(void* const* d_in, const int* in_sizes, int n_in,
                              void* d_out, int out_size, void* d_ws, size_t ws_size,
                              hipStream_t stream) {
    const float* pred   = (const float*)d_in[0];
    const float* target = (const float*)d_in[1];
    const float* Tarr   = (const float*)d_in[2];
    const float* g      = (const float*)d_in[3];
    const float* dirs   = (const float*)d_in[4];
    const float* noise  = (const float*)d_in[5];
    const int B = in_sizes[2];  // T is (B,)

    float* partials = (float*)d_ws;
    float* out      = (float*)d_out;

    const int block = 256;
    const int grid  = (B + block - 1) / block;
    nrtl_loss_kernel<<<grid, block, 0, stream>>>(pred, target, Tarr, g, dirs, noise, partials, B);
    reduce_kernel<<<1, block, 0, stream>>>(partials, grid, out);
}

// Round 6
// 180.093 us; speedup vs baseline: 1.0714x; 1.0714x over previous
//
#include <hip/hip_runtime.h>

// MechanisticNRTLLoss — B=1e6 samples, scalar fp32 loss.
// R6: latency attack. Evidence R1-R5: time invariant to VALU count (R1 vs R2)
// and to coalescing (R5) -> each wave serializes ~30 dependent load drains
// (compiler sinks loads to uses; VGPR stayed 48 in R4 hoist attempt).
// Fix: 2 samples/thread, ALL loads issued first (float4/float2, consecutive
// rows), then __builtin_amdgcn_sched_barrier(0) pins them before compute ->
// one waitcnt drain instead of ~30. Math identical to R2/R4/R5.

constexpr float ALPHA    = 0.3f;
constexpr float R_GAS    = 8.314462618f;
constexpr float EPS      = 1e-12f;
constexpr float TAU_CLIP = 10.0f;
constexpr float LN_CLIP  = 20.0f;
constexpr float EPS_FD   = 1e-4f;

constexpr float LOG2E = 1.44269504088896340736f;
constexpr float LN2   = 0.69314718055994530942f;

__device__ __forceinline__ float clipf(float v, float lo, float hi) {
    return fminf(fmaxf(v, lo), hi);
}
__device__ __forceinline__ float fast_rcp(float x) { return __builtin_amdgcn_rcpf(x); }

struct Mats {
    float tau[3][3];
    float G[3][3];
    float tG[3][3];
};

__device__ __forceinline__ void ln_gamma3(const float x[3], const Mats& M, float lg[3]) {
    float ratio[3], invd[3];
#pragma unroll
    for (int i = 0; i < 3; ++i) {
        float d = x[0] * M.G[0][i] + x[1] * M.G[1][i] + x[2] * M.G[2][i];
        d = fmaxf(d, EPS);
        float A = x[0] * M.tG[0][i] + x[1] * M.tG[1][i] + x[2] * M.tG[2][i];
        float inv = fast_rcp(d);
        invd[i] = inv;
        ratio[i] = A * inv;
    }
#pragma unroll
    for (int i = 0; i < 3; ++i) {
        float s = ratio[i];
#pragma unroll
        for (int j = 0; j < 3; ++j) {
            s += x[j] * M.G[i][j] * invd[j] * (M.tau[i][j] - ratio[j]);
        }
        lg[i] = clipf(s, -LN_CLIP, LN_CLIP);
    }
}

__device__ __forceinline__ void renorm3(float x[3]) {
    x[0] = fmaxf(x[0], 0.0f);
    x[1] = fmaxf(x[1], 0.0f);
    x[2] = fmaxf(x[2], 0.0f);
    float inv = fast_rcp(fmaxf(x[0] + x[1] + x[2], EPS));
    x[0] *= inv; x[1] *= inv; x[2] *= inv;
}

// Full per-sample loss (weights applied except the final 1/B).
// dv: [d*3+k] for d<2; nv: [tr*3+k] for tr<4.
__device__ __forceinline__ float sample_loss(const float p6[6], const float t6[6], float Tv,
                                             const float gv[9], const float dv[6], const float nv[12])
{
    float sup = 0.0f;
#pragma unroll
    for (int k = 0; k < 6; ++k) {
        float d = p6[k] - t6[k];
        sup += d * d;
    }

    float xE[3] = {p6[0], p6[1], p6[2]};
    float xR[3] = {p6[3], p6[4], p6[5]};
    renorm3(xE);
    renorm3(xR);

    const float invRT = fast_rcp(R_GAS * fmaxf(Tv, 1.0f));
    Mats M;
#pragma unroll
    for (int a = 0; a < 3; ++a) {
#pragma unroll
        for (int b = 0; b < 3; ++b) {
            float ta = clipf(gv[a * 3 + b] * invRT, -TAU_CLIP, TAU_CLIP);
            float Gv = __builtin_amdgcn_exp2f((-ALPHA * LOG2E) * ta);
            M.tau[a][b] = ta;
            M.G[a][b]   = Gv;
            M.tG[a][b]  = ta * Gv;
        }
    }

    float lgE[3], lgR[3];
    ln_gamma3(xE, M, lgE);
    ln_gamma3(xR, M, lgR);

    float logxE[3];
    float phy = 0.0f;
#pragma unroll
    for (int k = 0; k < 3; ++k) {
        logxE[k] = LN2 * __builtin_amdgcn_logf(fmaxf(xE[k], EPS));
        float logxR = LN2 * __builtin_amdgcn_logf(fmaxf(xR[k], EPS));
        float r = logxE[k] + lgE[k] - logxR - lgR[k];
        phy += r * r;
    }

    float gdsum = 0.0f;
#pragma unroll
    for (int d = 0; d < 2; ++d) {
        float xp[3], xm[3];
#pragma unroll
        for (int k = 0; k < 3; ++k) {
            float dvk = dv[d * 3 + k];
            xp[k] = xE[k] + EPS_FD * dvk;
            xm[k] = xE[k] - EPS_FD * dvk;
        }
        renorm3(xp);
        renorm3(xm);
        float lgp[3], lgm[3];
        ln_gamma3(xp, M, lgp);
        ln_gamma3(xm, M, lgm);
        float gd = 0.0f;
        const float inv2e = 0.5f / EPS_FD;
#pragma unroll
        for (int k = 0; k < 3; ++k) gd += xE[k] * ((lgp[k] - lgm[k]) * inv2e);
        gdsum += gd * gd;
    }

    float tpdsum = 0.0f;
#pragma unroll
    for (int tr = 0; tr < 4; ++tr) {
        float w[3];
#pragma unroll
        for (int k = 0; k < 3; ++k) w[k] = xE[k] + nv[tr * 3 + k];
        renorm3(w);
        float lgw[3];
        ln_gamma3(w, M, lgw);
        float tpd = 0.0f;
#pragma unroll
        for (int k = 0; k < 3; ++k) {
            float logw = LN2 * __builtin_amdgcn_logf(fmaxf(w[k], EPS));
            tpd += w[k] * (logw + lgw[k] - logxE[k] - lgE[k]);
        }
        tpdsum += fmaxf(-tpd, 0.0f);  // MARGIN = 0
    }

    return sup * (1.0f / 6.0f) + phy * (1.0f / 3.0f) + 0.05f * gdsum + 0.025f * tpdsum;
}

__global__ __launch_bounds__(256) void nrtl_loss_kernel(
    const float* __restrict__ pred,   // (B,6)
    const float* __restrict__ target, // (B,6)
    const float* __restrict__ Tarr,   // (B,)
    const float* __restrict__ g,      // (B,3,3)
    const float* __restrict__ dirs,   // (2,B,3)
    const float* __restrict__ noise,  // (4,B,3)
    float* __restrict__ partials, int B)
{
    const int tid = blockIdx.x * blockDim.x + threadIdx.x;
    const int i0  = tid * 2;   // two consecutive samples per thread (i0 even)
    float contrib = 0.0f;

    if (i0 + 1 < B) {
        // ===== load phase: 34 independent VMEM ops, pinned before compute ====
        float pl[12], tl[12], gl[18], dl[12], nl[24], Tl[2];
        {
            const float4* pp = (const float4*)(pred + (size_t)i0 * 6);    // 48B/thread, 16B-aligned
            *(float4*)(pl + 0) = pp[0];
            *(float4*)(pl + 4) = pp[1];
            *(float4*)(pl + 8) = pp[2];
            const float4* tp = (const float4*)(target + (size_t)i0 * 6);
            *(float4*)(tl + 0) = tp[0];
            *(float4*)(tl + 4) = tp[1];
            *(float4*)(tl + 8) = tp[2];
            *(float2*)Tl = *(const float2*)(Tarr + i0);                   // 8B-aligned
            const float2* gp = (const float2*)(g + (size_t)i0 * 9);       // 72B/thread, 8B-aligned
#pragma unroll
            for (int k = 0; k < 9; ++k) *(float2*)(gl + 2 * k) = gp[k];
#pragma unroll
            for (int d = 0; d < 2; ++d) {
                const float2* dp = (const float2*)(dirs + ((size_t)d * B + i0) * 3);
                *(float2*)(dl + d * 6 + 0) = dp[0];
                *(float2*)(dl + d * 6 + 2) = dp[1];
                *(float2*)(dl + d * 6 + 4) = dp[2];
            }
#pragma unroll
            for (int tr = 0; tr < 4; ++tr) {
                const float2* np = (const float2*)(noise + ((size_t)tr * B + i0) * 3);
                *(float2*)(nl + tr * 6 + 0) = np[0];
                *(float2*)(nl + tr * 6 + 2) = np[1];
                *(float2*)(nl + tr * 6 + 4) = np[2];
            }
        }
        __builtin_amdgcn_sched_barrier(0);   // loads may NOT be sunk past here

        // ===== unpack (register renames, free) =====
        float p0[6] = {pl[0], pl[1], pl[2], pl[3], pl[4], pl[5]};
        float p1[6] = {pl[6], pl[7], pl[8], pl[9], pl[10], pl[11]};
        float t0[6] = {tl[0], tl[1], tl[2], tl[3], tl[4], tl[5]};
        float t1[6] = {tl[6], tl[7], tl[8], tl[9], tl[10], tl[11]};
        float g0[9] = {gl[0], gl[1], gl[2], gl[3], gl[4], gl[5], gl[6], gl[7], gl[8]};
        float g1[9] = {gl[9], gl[10], gl[11], gl[12], gl[13], gl[14], gl[15], gl[16], gl[17]};
        float dv0[6] = {dl[0], dl[1], dl[2], dl[6], dl[7], dl[8]};
        float dv1[6] = {dl[3], dl[4], dl[5], dl[9], dl[10], dl[11]};
        float nv0[12] = {nl[0],  nl[1],  nl[2],  nl[6],  nl[7],  nl[8],
                         nl[12], nl[13], nl[14], nl[18], nl[19], nl[20]};
        float nv1[12] = {nl[3],  nl[4],  nl[5],  nl[9],  nl[10], nl[11],
                         nl[15], nl[16], nl[17], nl[21], nl[22], nl[23]};

        contrib  = sample_loss(p0, t0, Tl[0], g0, dv0, nv0);
        contrib += sample_loss(p1, t1, Tl[1], g1, dv1, nv1);
    } else if (i0 < B) {
        // tail (only reachable for odd B): scalar single-sample path
        float p0[6], t0[6], g0[9], dv0[6], nv0[12];
#pragma unroll
        for (int k = 0; k < 6; ++k) { p0[k] = pred[(size_t)i0 * 6 + k]; t0[k] = target[(size_t)i0 * 6 + k]; }
#pragma unroll
        for (int k = 0; k < 9; ++k) g0[k] = g[(size_t)i0 * 9 + k];
#pragma unroll
        for (int d = 0; d < 2; ++d)
#pragma unroll
            for (int k = 0; k < 3; ++k) dv0[d * 3 + k] = dirs[((size_t)d * B + i0) * 3 + k];
#pragma unroll
        for (int tr = 0; tr < 4; ++tr)
#pragma unroll
            for (int k = 0; k < 3; ++k) nv0[tr * 3 + k] = noise[((size_t)tr * B + i0) * 3 + k];
        contrib = sample_loss(p0, t0, Tarr[i0], g0, dv0, nv0);
    }

    contrib *= 1.0f / (float)B;

    // ---- block reduction: wave shuffle then LDS across 4 waves ----
#pragma unroll
    for (int off = 32; off > 0; off >>= 1)
        contrib += __shfl_down(contrib, off, 64);

    __shared__ float ssum[4];
    const int lane = threadIdx.x & 63;
    const int wid  = threadIdx.x >> 6;
    if (lane == 0) ssum[wid] = contrib;
    __syncthreads();
    if (threadIdx.x == 0) {
        partials[blockIdx.x] = ssum[0] + ssum[1] + ssum[2] + ssum[3];
    }
}

__global__ __launch_bounds__(256) void reduce_kernel(
    const float* __restrict__ partials, int n, float* __restrict__ out)
{
    double sacc = 0.0;
    for (int j = threadIdx.x; j < n; j += 256) sacc += (double)partials[j];
#pragma unroll
    for (int off = 32; off > 0; off >>= 1)
        sacc += __shfl_down(sacc, off, 64);
    __shared__ double ds[4];
    const int lane = threadIdx.x & 63;
    const int wid  = threadIdx.x >> 6;
    if (lane == 0) ds[wid] = sacc;
    __syncthreads();
    if (threadIdx.x == 0) out[0] = (float)(ds[0] + ds[1] + ds[2] + ds[3]);
}

extern "C" void kernel_launch(void* const* d_in, const int* in_sizes, int n_in,
                              void* d_out, int out_size, void* d_ws, size_t ws_size,
                              hipStream_t stream) {
    const float* pred   = (const float*)d_in[0];
    const float* target = (const float*)d_in[1];
    const float* Tarr   = (const float*)d_in[2];
    const float* g      = (const float*)d_in[3];
    const float* dirs   = (const float*)d_in[4];
    const float* noise  = (const float*)d_in[5];
    const int B = in_sizes[2];  // T is (B,)

    float* partials = (float*)d_ws;
    float* out      = (float*)d_out;

    const int block = 256;
    const int grid  = (B + 2 * block - 1) / (2 * block);   // 2 samples/thread
    nrtl_loss_kernel<<<grid, block, 0, stream>>>(pred, target, Tarr, g, dirs, noise, partials, B);
    reduce_kernel<<<1, block, 0, stream>>>(partials, grid, out);
}